// Round 1
// baseline (374.290 us; speedup 1.0000x reference)
//
#include <hip/hip_runtime.h>
#include <stdint.h>
#include <math.h>

// ============================================================================
// MultiScaleWalkSampler — exact replay of the JAX reference RNG.
//
// RNG assumption (documented for future rounds): JAX >= 0.4.36 defaults,
// i.e. jax_threefry_partitionable = True:
//   split(key, n)[i]      = threefry2x32(key, (0, i))          (y0, y1) pair
//   random_bits32(key)[j] = y0 ^ y1  of threefry2x32(key,(0,j))
// If validation fails wholesale, switch to the "original" mode:
//   counts = iota(size), halves paired (j, j+size/2), out = concat(y0s, y1s).
// ============================================================================

namespace {

constexpr int kB   = 8192;
constexpr int kWS  = 10, kLS = 3;
constexpr int kWL  = 5,  kLL = 10;
constexpr int kWT  = 5,  kLT = 8;
constexpr int kBWS = kB * kWS;            // 81920
constexpr int kBWL = kB * kWL;            // 40960
constexpr int kBWT = kB * kWT;            // 40960
constexpr int kTotal = kBWS + kBWL + kBWT;  // 163840

// Output float offsets (return-order concat: short(n,t,m), long(n,t,m),
// tawr(n,t,m,rflag,rho))
constexpr int O_SN = 0;
constexpr int O_ST = O_SN + kBWS * kLS;
constexpr int O_SM = O_ST + kBWS * kLS;
constexpr int O_LN = O_SM + kBWS * kLS;     // 737280
constexpr int O_LT = O_LN + kBWL * kLL;
constexpr int O_LM = O_LT + kBWL * kLL;
constexpr int O_TN = O_LM + kBWL * kLL;     // 1966080
constexpr int O_TT = O_TN + kBWT * kLT;
constexpr int O_TM = O_TT + kBWT * kLT;
constexpr int O_TR = O_TM + kBWT * kLT;
constexpr int O_TQ = O_TR + kBWT * kLT;     // total = 3604480

struct Keys {
  uint32_t sk[kLS - 1][2];   // short-walk per-step categorical keys
  uint32_t lk[kLL - 1][2];   // long-walk per-step categorical keys
  uint32_t tu[kLT - 1][2];   // tawr per-step uniform(restart) keys
  uint32_t tc[kLT - 1][2];   // tawr per-step categorical keys
};

}  // namespace

// ---------------------------------------------------------------------------
// threefry2x32 (JAX rotation schedule), host+device
// ---------------------------------------------------------------------------
__host__ __device__ static inline void tf2x32(uint32_t k0, uint32_t k1,
                                              uint32_t x0, uint32_t x1,
                                              uint32_t& o0, uint32_t& o1) {
  uint32_t ks2 = k0 ^ k1 ^ 0x1BD11BDAu;
#define TFR(r) { x0 += x1; x1 = (x1 << (r)) | (x1 >> (32 - (r))); x1 ^= x0; }
  x0 += k0; x1 += k1;
  TFR(13) TFR(15) TFR(26) TFR(6)
  x0 += k1;  x1 += ks2 + 1u;
  TFR(17) TFR(29) TFR(16) TFR(24)
  x0 += ks2; x1 += k0 + 2u;
  TFR(13) TFR(15) TFR(26) TFR(6)
  x0 += k0;  x1 += k1 + 3u;
  TFR(17) TFR(29) TFR(16) TFR(24)
  x0 += k1;  x1 += ks2 + 4u;
  TFR(13) TFR(15) TFR(26) TFR(6)
  x0 += ks2; x1 += k0 + 5u;
#undef TFR
  o0 = x0; o1 = x1;
}

__device__ __forceinline__ uint32_t rbits32(uint32_t k0, uint32_t k1, uint32_t j) {
  uint32_t a, b;
  tf2x32(k0, k1, 0u, j, a, b);
  return a ^ b;   // partitionable-mode 32-bit draw
}

__device__ __forceinline__ float bits_to_u01(uint32_t bits) {
  // jax uniform: bitcast((bits>>9)|0x3f800000) - 1.0  in [0,1)
  return __uint_as_float((bits >> 9) | 0x3f800000u) - 1.0f;
}

__device__ __forceinline__ float gumbel_of(uint32_t k0, uint32_t k1, uint32_t j) {
  float u = bits_to_u01(rbits32(k0, k1, j));
  if (u == 0.0f) u = 1.17549435e-38f;   // max(tiny, u + tiny) semantics
  return -logf(-logf(u));               // ocml log, same as XLA ROCm lowering
}

// ---------------------------------------------------------------------------
// categorical over one neighbor row (32 entries), gumbel-argmax, first-index
// tie-break (strict > while scanning ascending d). Tracks the chosen time so
// we never index a register array at runtime (avoids scratch, rule #20).
// ---------------------------------------------------------------------------
struct CatRes { int idx; float bt; bool has; };

__device__ __forceinline__ CatRes categorical32(uint32_t k0, uint32_t k1,
                                                uint32_t j0,
                                                const float* __restrict__ row_t,
                                                float t) {
  CatRes r; r.idx = 0; r.bt = 0.0f; r.has = false;
  float best = -INFINITY;
  const float4* row4 = (const float4*)row_t;
#pragma unroll 2
  for (int q = 0; q < 8; ++q) {
    float4 v4 = row4[q];
    float nv0 = v4.x, nv1 = v4.y, nv2 = v4.z, nv3 = v4.w;
#define CAT_ONE(E, NV)                                                       \
    {                                                                        \
      int d = q * 4 + (E);                                                   \
      float ntd = (NV);                                                      \
      bool valid = ntd < t;                                                  \
      r.has |= valid;                                                        \
      float g = gumbel_of(k0, k1, j0 + (uint32_t)d);                         \
      float logit = valid ? __fdiv_rn(ntd, 0.1f) : -1e30f;                   \
      float v = __fadd_rn(g, logit);                                         \
      if (v > best) { best = v; r.idx = d; r.bt = ntd; }                     \
    }
    CAT_ONE(0, nv0) CAT_ONE(1, nv1) CAT_ONE(2, nv2) CAT_ONE(3, nv3)
#undef CAT_ONE
  }
  return r;
}

// ---------------------------------------------------------------------------
// plain temporal-biased walk (short / long)
// ---------------------------------------------------------------------------
template <int W, int L>
__device__ void plain_walk(int bw, const uint32_t keys[][2],
                           const int* __restrict__ src, const float* __restrict__ ct,
                           const int* __restrict__ nbi, const float* __restrict__ nbt,
                           float* __restrict__ on, float* __restrict__ ot,
                           float* __restrict__ om) {
  int b = bw / W;
  int cur = src[b];
  float t = ct[b];
  int obase = bw * L;
  on[obase] = (float)cur; ot[obase] = t; om[obase] = 1.0f;
  bool alive = true;
  for (int s = 0; s < L - 1; ++s) {
    float wn = 0.0f, wt = 0.0f, wm = 0.0f;
    if (alive) {
      uint32_t j0 = (uint32_t)bw * 32u;
      CatRes c = categorical32(keys[s][0], keys[s][1], j0,
                               nbt + (size_t)cur * 32, t);
      if (c.has) {
        cur = nbi[(size_t)cur * 32 + c.idx];
        t = c.bt;
        wn = (float)cur; wt = t; wm = 1.0f;
      } else {
        alive = false;
      }
    }
    int o = obase + s + 1;
    on[o] = wn; ot[o] = wt; om[o] = wm;
  }
}

// ---------------------------------------------------------------------------
// TAWR walk with learnable restart
// ---------------------------------------------------------------------------
__device__ void tawr_walk(int bw, const Keys& K,
                          const int* __restrict__ src, const float* __restrict__ ct,
                          const int* __restrict__ nbi, const float* __restrict__ nbt,
                          const float* __restrict__ mem, const float* __restrict__ rw,
                          const float* __restrict__ rb, const float* __restrict__ tw,
                          const float* __restrict__ tb,
                          float* __restrict__ on, float* __restrict__ ot,
                          float* __restrict__ om, float* __restrict__ orf,
                          float* __restrict__ orh) {
  int b = bw / kWT;
  int n0 = src[b];
  float t0 = ct[b];
  float rbv = rb[0];
  int cur = n0;
  float t = t0;
  int obase = bw * kLT;
  on[obase] = (float)n0; ot[obase] = t0; om[obase] = 1.0f;
  orf[obase] = 0.0f; orh[obase] = 0.0f;
  bool alive = true;

  for (int s = 0; s < kLT - 1; ++s) {
    float wn = 0.0f, wt = 0.0f, wm = 0.0f, wr = 0.0f, wq = 0.0f;
    if (alive) {
      // rho = sigmoid([mem || cos(t*tw+tb)] . rw + rb), sequential-K order,
      // no FMA contraction (__f*_rn) to mimic XLA's non-contracted fp.
      float acc = 0.0f;
      const float4* mrow = (const float4*)(mem + (size_t)cur * 128);
      const float4* rw4 = (const float4*)rw;
#pragma unroll 4
      for (int q = 0; q < 32; ++q) {
        float4 a = mrow[q];
        float4 w = rw4[q];
        acc = __fadd_rn(acc, __fmul_rn(a.x, w.x));
        acc = __fadd_rn(acc, __fmul_rn(a.y, w.y));
        acc = __fadd_rn(acc, __fmul_rn(a.z, w.z));
        acc = __fadd_rn(acc, __fmul_rn(a.w, w.w));
      }
#pragma unroll 4
      for (int j = 0; j < 64; ++j) {
        float phi = cosf(__fadd_rn(__fmul_rn(t, tw[j]), tb[j]));
        acc = __fadd_rn(acc, __fmul_rn(phi, rw[128 + j]));
      }
      float z = __fadd_rn(acc, rbv);
      // sigmoid: modern XLA MLIR emitter form 1/(1+exp(-x)).
      float rho = __fdiv_rn(1.0f, __fadd_rn(1.0f, expf(-z)));

      float u = bits_to_u01(rbits32(K.tu[s][0], K.tu[s][1], (uint32_t)bw));
      bool restart = u < rho;

      bool has = false;
      int nn = 0;
      float ntm = 0.0f;
      if (!restart) {
        uint32_t j0 = (uint32_t)bw * 32u;
        CatRes c = categorical32(K.tc[s][0], K.tc[s][1], j0,
                                 nbt + (size_t)cur * 32, t);
        has = c.has;
        if (has) {
          nn = nbi[(size_t)cur * 32 + c.idx];
          ntm = c.bt;
        }
      } else {
        nn = n0;
        ntm = t0;
      }

      if (restart || has) {
        cur = nn; t = ntm;
        wn = (float)nn; wt = ntm; wm = 1.0f;
        wr = restart ? 1.0f : 0.0f;
        wq = rho;
      } else {
        alive = false;
      }
    }
    int o = obase + s + 1;
    on[o] = wn; ot[o] = wt; om[o] = wm; orf[o] = wr; orh[o] = wq;
  }
}

// ---------------------------------------------------------------------------
// fused kernel: [0,81920) short, [81920,122880) long, [122880,163840) tawr.
// Boundaries are multiples of 256 -> no intra-block walk-type divergence.
// ---------------------------------------------------------------------------
__global__ __launch_bounds__(256) void walks_kernel(
    const int* __restrict__ src, const float* __restrict__ ct,
    const int* __restrict__ nbi, const float* __restrict__ nbt,
    const float* __restrict__ mem, const float* __restrict__ rw,
    const float* __restrict__ rb, const float* __restrict__ tw,
    const float* __restrict__ tb, float* __restrict__ out, Keys K) {
  int tid = blockIdx.x * blockDim.x + threadIdx.x;
  if (tid >= kTotal) return;
  if (tid < kBWS) {
    plain_walk<kWS, kLS>(tid, K.sk, src, ct, nbi, nbt,
                         out + O_SN, out + O_ST, out + O_SM);
  } else if (tid < kBWS + kBWL) {
    plain_walk<kWL, kLL>(tid - kBWS, K.lk, src, ct, nbi, nbt,
                         out + O_LN, out + O_LT, out + O_LM);
  } else {
    tawr_walk(tid - kBWS - kBWL, K, src, ct, nbi, nbt, mem, rw, rb, tw, tb,
              out + O_TN, out + O_TT, out + O_TM, out + O_TR, out + O_TQ);
  }
}

// ---------------------------------------------------------------------------
extern "C" void kernel_launch(void* const* d_in, const int* in_sizes, int n_in,
                              void* d_out, int out_size, void* d_ws, size_t ws_size,
                              hipStream_t stream) {
  (void)in_sizes; (void)n_in; (void)out_size; (void)d_ws; (void)ws_size;

  const int*   src = (const int*)d_in[0];
  const float* ct  = (const float*)d_in[1];
  const int*   nbi = (const int*)d_in[2];
  const float* nbt = (const float*)d_in[3];
  const float* mem = (const float*)d_in[4];
  const float* rw  = (const float*)d_in[5];
  const float* rb  = (const float*)d_in[6];
  const float* tw  = (const float*)d_in[7];
  const float* tb  = (const float*)d_in[8];
  float* out = (float*)d_out;

  // Host-side key schedule (pure integer threefry; deterministic per call).
  // base key for seed 42 is (0, 42).
  Keys K;
  uint32_t k1[2], k2[2], k3[2];
  tf2x32(0u, 42u, 0u, 0u, k1[0], k1[1]);   // split(key,3)[0]
  tf2x32(0u, 42u, 0u, 1u, k2[0], k2[1]);   // split(key,3)[1]
  tf2x32(0u, 42u, 0u, 2u, k3[0], k3[1]);   // split(key,3)[2]
  for (uint32_t s = 0; s < kLS - 1; ++s)
    tf2x32(k1[0], k1[1], 0u, s, K.sk[s][0], K.sk[s][1]);
  for (uint32_t s = 0; s < kLL - 1; ++s)
    tf2x32(k2[0], k2[1], 0u, s, K.lk[s][0], K.lk[s][1]);
  for (uint32_t s = 0; s < kLT - 1; ++s) {
    uint32_t ks[2];
    tf2x32(k3[0], k3[1], 0u, s, ks[0], ks[1]);       // scan step key
    tf2x32(ks[0], ks[1], 0u, 0u, K.tu[s][0], K.tu[s][1]);  // k1: restart uniform
    tf2x32(ks[0], ks[1], 0u, 1u, K.tc[s][0], K.tc[s][1]);  // k2: categorical
  }

  dim3 grid((kTotal + 255) / 256);
  walks_kernel<<<grid, dim3(256), 0, stream>>>(src, ct, nbi, nbt, mem, rw, rb,
                                               tw, tb, out, K);
}

// Round 6
// 328.860 us; speedup vs baseline: 1.1381x; 1.1381x over previous
//
#include <hip/hip_runtime.h>
#include <stdint.h>
#include <math.h>

// ============================================================================
// MultiScaleWalkSampler — exact replay of the JAX reference RNG (verified
// round 1: absmax == 0.0 with partitionable threefry + sequential-K dot +
// ocml logf/cosf/expf + no FMA contraction).
//
// Rounds 2-5 (resubmit; benches were GPU-acquisition timeouts, kernel never
// measured): latency-bound (VALUBusy 47%, occ 11.9%) -> G=4 lanes per walk,
// two kernels (plain / tawr), LDS-staged exact-order rho reduction.
// ============================================================================

namespace {

constexpr int kB   = 8192;
constexpr int kWS  = 10, kLS = 3;
constexpr int kWL  = 5,  kLL = 10;
constexpr int kWT  = 5,  kLT = 8;
constexpr int kBWS = kB * kWS;            // 81920
constexpr int kBWL = kB * kWL;            // 40960
constexpr int kBWT = kB * kWT;            // 40960

// Output float offsets (return-order concat: short(n,t,m), long(n,t,m),
// tawr(n,t,m,rflag,rho))
constexpr int O_SN = 0;
constexpr int O_ST = O_SN + kBWS * kLS;
constexpr int O_SM = O_ST + kBWS * kLS;
constexpr int O_LN = O_SM + kBWS * kLS;
constexpr int O_LT = O_LN + kBWL * kLL;
constexpr int O_LM = O_LT + kBWL * kLL;
constexpr int O_TN = O_LM + kBWL * kLL;
constexpr int O_TT = O_TN + kBWT * kLT;
constexpr int O_TM = O_TT + kBWT * kLT;
constexpr int O_TR = O_TM + kBWT * kLT;
constexpr int O_TQ = O_TR + kBWT * kLT;

struct Keys {
  uint32_t sk[kLS - 1][2];
  uint32_t lk[kLL - 1][2];
  uint32_t tu[kLT - 1][2];
  uint32_t tc[kLT - 1][2];
};

constexpr int kSlotStride = 68;   // floats; 68 = 64 + pad -> 2-way banks, 16B-aligned rows

}  // namespace

// ---------------------------------------------------------------------------
// threefry2x32 (JAX rotation schedule), host+device
// ---------------------------------------------------------------------------
__host__ __device__ static inline void tf2x32(uint32_t k0, uint32_t k1,
                                              uint32_t x0, uint32_t x1,
                                              uint32_t& o0, uint32_t& o1) {
  uint32_t ks2 = k0 ^ k1 ^ 0x1BD11BDAu;
#define TFR(r) { x0 += x1; x1 = (x1 << (r)) | (x1 >> (32 - (r))); x1 ^= x0; }
  x0 += k0; x1 += k1;
  TFR(13) TFR(15) TFR(26) TFR(6)
  x0 += k1;  x1 += ks2 + 1u;
  TFR(17) TFR(29) TFR(16) TFR(24)
  x0 += ks2; x1 += k0 + 2u;
  TFR(13) TFR(15) TFR(26) TFR(6)
  x0 += k0;  x1 += k1 + 3u;
  TFR(17) TFR(29) TFR(16) TFR(24)
  x0 += k1;  x1 += ks2 + 4u;
  TFR(13) TFR(15) TFR(26) TFR(6)
  x0 += ks2; x1 += k0 + 5u;
#undef TFR
  o0 = x0; o1 = x1;
}

__device__ __forceinline__ uint32_t rbits32(uint32_t k0, uint32_t k1, uint32_t j) {
  uint32_t a, b;
  tf2x32(k0, k1, 0u, j, a, b);
  return a ^ b;
}

__device__ __forceinline__ float bits_to_u01(uint32_t bits) {
  return __uint_as_float((bits >> 9) | 0x3f800000u) - 1.0f;
}

__device__ __forceinline__ float gumbel_of(uint32_t k0, uint32_t k1, uint32_t j) {
  float u = bits_to_u01(rbits32(k0, k1, j));
  if (u == 0.0f) u = 1.17549435e-38f;
  return -logf(-logf(u));
}

// ---------------------------------------------------------------------------
// 4-lane cooperative categorical over one 32-neighbor row.
// Lane r handles d in [8r, 8r+8); local strict-> scan ascending d, then
// 2-round xor-butterfly (larger value wins, tie -> smaller index) ==
// sequential first-index argmax. has <=> best > -1e29 (valid logits >= -4.5,
// invalid stay at -1e30 exactly in fp32).
// ---------------------------------------------------------------------------
struct Cat4 { int idx; float bt; bool has; };

__device__ __forceinline__ Cat4 categorical_g4(uint32_t k0, uint32_t k1,
                                               uint32_t j0,
                                               const float* __restrict__ row_t,
                                               float t, int r) {
  const float4* row4 = (const float4*)row_t;
  float4 v0 = row4[2 * r];
  float4 v1 = row4[2 * r + 1];
  float nv[8] = {v0.x, v0.y, v0.z, v0.w, v1.x, v1.y, v1.z, v1.w};
  float best = -INFINITY;
  int bidx = 0;
  float bbt = 0.0f;
#pragma unroll
  for (int e = 0; e < 8; ++e) {
    int d = 8 * r + e;
    float ntd = nv[e];
    bool valid = ntd < t;
    float g = gumbel_of(k0, k1, j0 + (uint32_t)d);
    float logit = valid ? __fdiv_rn(ntd, 0.1f) : -1e30f;
    float v = __fadd_rn(g, logit);
    if (v > best) { best = v; bidx = d; bbt = ntd; }
  }
#pragma unroll
  for (int m = 1; m <= 2; m <<= 1) {
    float ov = __shfl_xor(best, m);
    int   oi = __shfl_xor(bidx, m);
    float ob = __shfl_xor(bbt, m);
    if (ov > best || (ov == best && oi < bidx)) { best = ov; bidx = oi; bbt = ob; }
  }
  Cat4 c; c.idx = bidx; c.bt = bbt; c.has = best > -1e29f;
  return c;
}

// ---------------------------------------------------------------------------
// plain temporal-biased walk, 4 lanes per walk
// ---------------------------------------------------------------------------
template <int W, int L>
__device__ void plain_walk_g4(int bw, int r, const uint32_t keys[][2],
                              const int* __restrict__ src, const float* __restrict__ ct,
                              const int* __restrict__ nbi, const float* __restrict__ nbt,
                              float* __restrict__ on, float* __restrict__ ot,
                              float* __restrict__ om) {
  int b = bw / W;
  int cur = src[b];
  float t = ct[b];
  int obase = bw * L;
  if (r == 0) { on[obase] = (float)cur; ot[obase] = t; }
  else if (r == 1) { om[obase] = 1.0f; }
  bool alive = true;
  for (int s = 0; s < L - 1; ++s) {
    float wn = 0.0f, wt = 0.0f, wm = 0.0f;
    if (alive) {
      Cat4 c = categorical_g4(keys[s][0], keys[s][1], (uint32_t)bw * 32u,
                              nbt + (size_t)cur * 32, t, r);
      if (c.has) {
        cur = nbi[(size_t)cur * 32 + c.idx];
        t = c.bt;
        wn = (float)cur; wt = t; wm = 1.0f;
      } else {
        alive = false;
      }
    }
    int o = obase + s + 1;
    if (r == 0) on[o] = wn;
    else if (r == 1) ot[o] = wt;
    else if (r == 2) om[o] = wm;
  }
}

__global__ __launch_bounds__(256) void plain_kernel(
    const int* __restrict__ src, const float* __restrict__ ct,
    const int* __restrict__ nbi, const float* __restrict__ nbt,
    float* __restrict__ out, Keys K) {
  int tid = blockIdx.x * blockDim.x + threadIdx.x;
  int gid = tid >> 2;
  int r = tid & 3;
  if (gid < kBWL) {   // long walks first (heavier): better backfill
    plain_walk_g4<kWL, kLL>(gid, r, K.lk, src, ct, nbi, nbt,
                            out + O_LN, out + O_LT, out + O_LM);
  } else {
    plain_walk_g4<kWS, kLS>(gid - kBWL, r, K.sk, src, ct, nbi, nbt,
                            out + O_SN, out + O_ST, out + O_SM);
  }
}

// ---------------------------------------------------------------------------
// TAWR walk, 4 lanes per walk. rho = sigmoid(seq-order dot + b): products are
// computed 16-per-lane, staged in LDS, and re-accumulated by every lane in
// strict sequential index order -> bit-identical to reference.
// Three phases of 64 products reuse one 64-float (+4 pad) slot per walk.
// LDS ops from one wave complete in order; compiler fences stop IR reordering.
// ---------------------------------------------------------------------------
__device__ void tawr_g4(int bw, int r, float* __restrict__ slot, const Keys& K,
                        const int* __restrict__ src, const float* __restrict__ ct,
                        const int* __restrict__ nbi, const float* __restrict__ nbt,
                        const float* __restrict__ mem, const float* __restrict__ rw,
                        const float* __restrict__ rb, const float* __restrict__ tw,
                        const float* __restrict__ tb,
                        float* __restrict__ on, float* __restrict__ ot,
                        float* __restrict__ om, float* __restrict__ orf,
                        float* __restrict__ orh) {
  int b = bw / kWT;
  int n0 = src[b];
  float t0 = ct[b];
  float rbv = rb[0];
  int cur = n0;
  float t = t0;
  int obase = bw * kLT;
  if (r == 0) { on[obase] = (float)n0; ot[obase] = t0; }
  else if (r == 1) { om[obase] = 1.0f; orf[obase] = 0.0f; }
  else if (r == 2) { orh[obase] = 0.0f; }
  bool alive = true;

  const float4* rw4 = (const float4*)rw;
  const float4* tw4 = (const float4*)tw;
  const float4* tb4 = (const float4*)tb;

  for (int s = 0; s < kLT - 1; ++s) {
    float wn = 0.0f, wt = 0.0f, wm = 0.0f, wr = 0.0f, wq = 0.0f;
    if (alive) {
      const float4* mrow = (const float4*)(mem + (size_t)cur * 128);
      float acc = 0.0f;
      // ---- phase A/B: mem products k in [0,64) then [64,128), exact order
#pragma unroll
      for (int ph = 0; ph < 2; ++ph) {
#pragma unroll
        for (int q = 0; q < 4; ++q) {
          int f4 = 16 * ph + 4 * r + q;
          float4 a = mrow[f4];
          float4 w = rw4[f4];
          float4 p;
          p.x = __fmul_rn(a.x, w.x); p.y = __fmul_rn(a.y, w.y);
          p.z = __fmul_rn(a.z, w.z); p.w = __fmul_rn(a.w, w.w);
          *(float4*)(slot + 16 * r + 4 * q) = p;
        }
        asm volatile("" ::: "memory");
#pragma unroll
        for (int q = 0; q < 16; ++q) {
          float4 p = *(const float4*)(slot + 4 * q);
          acc = __fadd_rn(acc, p.x); acc = __fadd_rn(acc, p.y);
          acc = __fadd_rn(acc, p.z); acc = __fadd_rn(acc, p.w);
        }
        asm volatile("" ::: "memory");
      }
      // ---- phase C: phi products j in [0,64), exact order
#pragma unroll
      for (int q = 0; q < 4; ++q) {
        int f4 = 4 * r + q;
        float4 w = tw4[f4];
        float4 bb = tb4[f4];
        float4 rwp = rw4[32 + f4];
        float4 p;
        p.x = __fmul_rn(cosf(__fadd_rn(__fmul_rn(t, w.x), bb.x)), rwp.x);
        p.y = __fmul_rn(cosf(__fadd_rn(__fmul_rn(t, w.y), bb.y)), rwp.y);
        p.z = __fmul_rn(cosf(__fadd_rn(__fmul_rn(t, w.z), bb.z)), rwp.z);
        p.w = __fmul_rn(cosf(__fadd_rn(__fmul_rn(t, w.w), bb.w)), rwp.w);
        *(float4*)(slot + 16 * r + 4 * q) = p;
      }
      asm volatile("" ::: "memory");
#pragma unroll
      for (int q = 0; q < 16; ++q) {
        float4 p = *(const float4*)(slot + 4 * q);
        acc = __fadd_rn(acc, p.x); acc = __fadd_rn(acc, p.y);
        acc = __fadd_rn(acc, p.z); acc = __fadd_rn(acc, p.w);
      }
      asm volatile("" ::: "memory");

      float z = __fadd_rn(acc, rbv);
      float rho = __fdiv_rn(1.0f, __fadd_rn(1.0f, expf(-z)));
      float u = bits_to_u01(rbits32(K.tu[s][0], K.tu[s][1], (uint32_t)bw));
      bool restart = u < rho;

      bool has = false;
      int nn = 0;
      float ntm = 0.0f;
      if (!restart) {
        Cat4 c = categorical_g4(K.tc[s][0], K.tc[s][1], (uint32_t)bw * 32u,
                                nbt + (size_t)cur * 32, t, r);
        has = c.has;
        if (has) {
          nn = nbi[(size_t)cur * 32 + c.idx];
          ntm = c.bt;
        }
      } else {
        nn = n0;
        ntm = t0;
      }

      if (restart || has) {
        cur = nn; t = ntm;
        wn = (float)nn; wt = ntm; wm = 1.0f;
        wr = restart ? 1.0f : 0.0f;
        wq = rho;
      } else {
        alive = false;
      }
    }
    int o = obase + s + 1;
    if (r == 0) { on[o] = wn; ot[o] = wt; }
    else if (r == 1) { om[o] = wm; orf[o] = wr; }
    else if (r == 2) { orh[o] = wq; }
  }
}

__global__ __launch_bounds__(256) void tawr_kernel(
    const int* __restrict__ src, const float* __restrict__ ct,
    const int* __restrict__ nbi, const float* __restrict__ nbt,
    const float* __restrict__ mem, const float* __restrict__ rw,
    const float* __restrict__ rb, const float* __restrict__ tw,
    const float* __restrict__ tb, float* __restrict__ out, Keys K) {
  __shared__ float plds[64 * kSlotStride];   // 17.4 KB
  int tid = blockIdx.x * blockDim.x + threadIdx.x;
  int gid = tid >> 2;
  int r = tid & 3;
  int ws = threadIdx.x >> 2;
  tawr_g4(gid, r, plds + ws * kSlotStride, K, src, ct, nbi, nbt, mem, rw, rb,
          tw, tb, out + O_TN, out + O_TT, out + O_TM, out + O_TR, out + O_TQ);
}

// ---------------------------------------------------------------------------
extern "C" void kernel_launch(void* const* d_in, const int* in_sizes, int n_in,
                              void* d_out, int out_size, void* d_ws, size_t ws_size,
                              hipStream_t stream) {
  (void)in_sizes; (void)n_in; (void)out_size; (void)d_ws; (void)ws_size;

  const int*   src = (const int*)d_in[0];
  const float* ct  = (const float*)d_in[1];
  const int*   nbi = (const int*)d_in[2];
  const float* nbt = (const float*)d_in[3];
  const float* mem = (const float*)d_in[4];
  const float* rw  = (const float*)d_in[5];
  const float* rb  = (const float*)d_in[6];
  const float* tw  = (const float*)d_in[7];
  const float* tb  = (const float*)d_in[8];
  float* out = (float*)d_out;

  Keys K;
  uint32_t k1[2], k2[2], k3[2];
  tf2x32(0u, 42u, 0u, 0u, k1[0], k1[1]);
  tf2x32(0u, 42u, 0u, 1u, k2[0], k2[1]);
  tf2x32(0u, 42u, 0u, 2u, k3[0], k3[1]);
  for (uint32_t s = 0; s < kLS - 1; ++s)
    tf2x32(k1[0], k1[1], 0u, s, K.sk[s][0], K.sk[s][1]);
  for (uint32_t s = 0; s < kLL - 1; ++s)
    tf2x32(k2[0], k2[1], 0u, s, K.lk[s][0], K.lk[s][1]);
  for (uint32_t s = 0; s < kLT - 1; ++s) {
    uint32_t ks[2];
    tf2x32(k3[0], k3[1], 0u, s, ks[0], ks[1]);
    tf2x32(ks[0], ks[1], 0u, 0u, K.tu[s][0], K.tu[s][1]);
    tf2x32(ks[0], ks[1], 0u, 1u, K.tc[s][0], K.tc[s][1]);
  }

  // tawr: 40960 walks * 4 lanes = 640 blocks; plain: 122880 * 4 = 1920 blocks
  tawr_kernel<<<dim3(640), dim3(256), 0, stream>>>(src, ct, nbi, nbt, mem, rw,
                                                   rb, tw, tb, out, K);
  plain_kernel<<<dim3(1920), dim3(256), 0, stream>>>(src, ct, nbi, nbt, out, K);
}